// Round 2
// baseline (257.764 us; speedup 1.0000x reference)
//
#include <hip/hip_runtime.h>

// Shapes (fixed): B=32, N=64, A=32, O=32, D=512, QD=512
// Inputs: 0:q(B,N,1,QD) f32  1:att1(B,N,A,O) f32  2:obj_reps(B,O,D) f32
//         3:tags(B,N,A) i32  4:t_rep(B,N,A,D) f32 5:W(QD,D) f32
//         6:bias f32 scalar  7:t i32 scalar
// Out: (B,N,O) f32
//
// Restructure: logits[bn,a] = sum_o att1[bn,a,o]*proj[bn,o] + inter[bn,:].t_rep[bn,a,:]
//   proj[bn,o] = inter[bn,:].obj_reps[b,o,:];  inter = q @ W
// Avoids materializing v (134 MB write+read). HBM floor ~= t_rep stream = 134 MB -> ~21 us.
// fp32 everywhere: logits std ~77 with near-one-hot softmax; bf16 noise can flip ties.
//
// Measurement model: same-binary repeatability +/-0.5-1 us. ~2 x 78 us poison fills
// (512 MB each) sit inside the timed window -> ~156 us fixed floor. Kernel-attributable
// portion ~= 75 us vs ~30 us floor (K1 ~7-12, K2 t_rep stream ~21, gaps ~5).
//
// R7 (512-thr K1): NEUTRAL (+0.9). K1 is throughput-bound (VALU-issue + LDS), not
// latency-bound; totals identical at 256/512 threads. Kept 512-thr variant.
//
// R8 DIAGNOSTIC: fused_att launched TWICE (idempotent - recomputes identical out;
// t_rep 134 MB streams both times, so delta == T2). De-blinds the K1/K2 split that
// the fill-dominated top-5 rocprof hides. Pre-committed reading:
//   delta >= 40 us -> K2 far off HBM floor, attack K2 streaming next.
//   delta ~= 20-28 -> K2 near floor; slack is K1/gaps; pivot or conclude.

typedef float floatx4 __attribute__((ext_vector_type(4)));

#define GM 2048   // B*N
#define GK 512    // QD
#define GN 512    // D

// ---------------- K1: inter = q @ W  (fp32 tiled GEMM, 64x64 tile, 512 thr, 4x2 utile)
// Per kk-step per thread: ds_read_b128(A, broadcast) + ds_read_b64(B, 2-way alias=free)
// + 8 v_fma_f32. Staging keeps adjacent lanes on adjacent addresses (coalesced) — do
// NOT trade this for wider LDS writes (R4/R5 lesson: -11 us).
#define BM 64
#define BN 64
#define BK 32
#define ASTRIDE (BM + 4)   // 68: rows stay 16B-aligned for ds_read_b128

__global__ __launch_bounds__(512) void gemm_qw(const float* __restrict__ A,
                                               const float* __restrict__ Bm,
                                               float* __restrict__ C) {
    __shared__ float As[BK][ASTRIDE];   // transposed: As[k][m]
    __shared__ float Bs[BK][BN];        // Bs[k][n]

    const int tid = threadIdx.x;
    const int bm0 = blockIdx.y * BM;
    const int bn0 = blockIdx.x * BN;

    // staging: A tile 64x32 = 512 float4 (1/thread), B tile 32x64 = 512 float4 (1/thread)
    const int ar = tid >> 3;            // 0..63 (A row)
    const int ak = (tid & 7) << 2;      // 0..28 (A k, x4) — adjacent lanes 16B apart
    const int br = tid >> 4;            // 0..31 (B k)
    const int bc = (tid & 15) << 2;     // 0..60 (B col, x4) — 16 lanes = 256B contiguous

    const int tx = tid & 31;            // output col pair (cols tx*2, tx*2+1)
    const int ty = tid >> 5;            // output row group (rows ty*4..+3)

    float acc[4][2] = {};

    const float* Ab = A + (long)bm0 * GK;
    const float* Bb = Bm + bn0;

    // prefetch tile 0
    float4 a0 = *(const float4*)(Ab + ar * GK + ak);
    float4 b0 = *(const float4*)(Bb + br * GN + bc);

    for (int k0 = 0; k0 < GK; k0 += BK) {
        __syncthreads();   // previous iteration's LDS reads done
        As[ak + 0][ar] = a0.x; As[ak + 1][ar] = a0.y;
        As[ak + 2][ar] = a0.z; As[ak + 3][ar] = a0.w;
        *(float4*)&Bs[br][bc] = b0;
        __syncthreads();

        if (k0 + BK < GK) {   // register prefetch of next K-tile hides global latency
            a0 = *(const float4*)(Ab + ar * GK + (k0 + BK) + ak);
            b0 = *(const float4*)(Bb + (k0 + BK + br) * GN + bc);
        }

#pragma unroll
        for (int kk = 0; kk < BK; ++kk) {
            float4 av = *(const float4*)&As[kk][ty * 4];   // broadcast across 32 lanes
            float2 bv = *(const float2*)&Bs[kk][tx * 2];   // 2-way bank alias (free)
            acc[0][0] += av.x * bv.x; acc[0][1] += av.x * bv.y;
            acc[1][0] += av.y * bv.x; acc[1][1] += av.y * bv.y;
            acc[2][0] += av.z * bv.x; acc[2][1] += av.z * bv.y;
            acc[3][0] += av.w * bv.x; acc[3][1] += av.w * bv.y;
        }
    }

#pragma unroll
    for (int i = 0; i < 4; ++i) {
        float2 v = make_float2(acc[i][0], acc[i][1]);
        *(float2*)(C + (long)(bm0 + ty * 4 + i) * GN + bn0 + tx * 2) = v;
    }
}

// ---------------- K2: fused proj/tdot/logits/softmax/output (merged + nt) ----------
// proj (L2) + tdot (HBM) in ONE loop: 2x memory-level parallelism per wave; inter_s
// read once for both dots. t_rep nontemporal: the 134 MB single-use stream must not
// evict obj_reps/att1 from L2. Measured -4.6 us vs separate loops (R4 vs R5).
__global__ __launch_bounds__(256) void fused_att(
    const float* __restrict__ att1, const float* __restrict__ obj_reps,
    const int* __restrict__ tags, const float* __restrict__ t_rep,
    const float* __restrict__ inter, const float* __restrict__ bias_p,
    const int* __restrict__ t_p, float* __restrict__ out) {
    const int bn = blockIdx.x;     // 0..2047
    const int b  = bn >> 6;        // N = 64
    const int tid = threadIdx.x;

    __shared__ float inter_s[512];
    __shared__ float att1_s[32 * 33];   // +1 pad: bank-conflict-free rows & cols
    __shared__ float proj_s[32];
    __shared__ float tdot_s[32];
    __shared__ float att2_s[32];

    // stage inter row (512 f32) and att1 tile (32x32 f32, padded)
    {
        float2 v = *(const float2*)(inter + bn * 512 + tid * 2);
        inter_s[tid * 2 + 0] = v.x;
        inter_s[tid * 2 + 1] = v.y;
    }
    {
        float4 v = *(const float4*)(att1 + bn * 1024 + tid * 4);
        int f = tid * 4;
        int r = f >> 5, c = f & 31;
        att1_s[r * 33 + c + 0] = v.x;
        att1_s[r * 33 + c + 1] = v.y;
        att1_s[r * 33 + c + 2] = v.z;
        att1_s[r * 33 + c + 3] = v.w;
    }
    __syncthreads();

    const int g = tid >> 3;   // 0..31: one row per 8-thread group
    const int j = tid & 7;    // lane within group

    {
        const float* pt = t_rep    + (bn * 32 + g) * 512;   // HBM stream (134 MB total)
        const float* po = obj_reps + (b  * 32 + g) * 512;   // L2-resident (2 MB)
        float st = 0.f, sp = 0.f;
#pragma unroll
        for (int i = 0; i < 16; ++i) {
            int d = i * 32 + j * 4;
            floatx4 tv = __builtin_nontemporal_load((const floatx4*)(pt + d));
            float4 ov = *(const float4*)(po + d);
            float i0 = inter_s[d + 0], i1 = inter_s[d + 1];
            float i2 = inter_s[d + 2], i3 = inter_s[d + 3];
            st += tv.x * i0 + tv.y * i1 + tv.z * i2 + tv.w * i3;
            sp += ov.x * i0 + ov.y * i1 + ov.z * i2 + ov.w * i3;
        }
        st += __shfl_xor(st, 1); st += __shfl_xor(st, 2); st += __shfl_xor(st, 4);
        sp += __shfl_xor(sp, 1); sp += __shfl_xor(sp, 2); sp += __shfl_xor(sp, 4);
        if (j == 0) { tdot_s[g] = st; proj_s[g] = sp; }
    }
    __syncthreads();

    // logits + masked softmax + renorm: threads 0..31 (all in wave 0)
    if (tid < 32) {
        const int a = tid;
        const float bias = *bias_p;
        const float tt = (float)(*t_p);
        float lsum = tdot_s[a] + bias;
#pragma unroll
        for (int o = 0; o < 32; ++o)
            lsum += att1_s[a * 33 + o] * proj_s[o];
        const float m = (float)tags[bn * 32 + a];
        float x = (lsum / tt) * m;     // masked slots -> logit 0, still in softmax
        float mx = x;
        mx = fmaxf(mx, __shfl_xor(mx, 1));
        mx = fmaxf(mx, __shfl_xor(mx, 2));
        mx = fmaxf(mx, __shfl_xor(mx, 4));
        mx = fmaxf(mx, __shfl_xor(mx, 8));
        mx = fmaxf(mx, __shfl_xor(mx, 16));
        float e = __expf(x - mx);
        float den = e;
        den += __shfl_xor(den, 1);
        den += __shfl_xor(den, 2);
        den += __shfl_xor(den, 4);
        den += __shfl_xor(den, 8);
        den += __shfl_xor(den, 16);
        float s = (e / den) * m;
        float ss = s;
        ss += __shfl_xor(ss, 1);
        ss += __shfl_xor(ss, 2);
        ss += __shfl_xor(ss, 4);
        ss += __shfl_xor(ss, 8);
        ss += __shfl_xor(ss, 16);
        att2_s[a] = s / (ss + 1e-13f);
    }
    __syncthreads();

    // out[bn,o] = sum_a att2[a] * att1[a,o]
    if (tid < 32) {
        const int o = tid;
        float s = 0.f;
#pragma unroll
        for (int a = 0; a < 32; ++a)
            s += att2_s[a] * att1_s[a * 33 + o];
        out[bn * 32 + o] = s;
    }
}

extern "C" void kernel_launch(void* const* d_in, const int* in_sizes, int n_in,
                              void* d_out, int out_size, void* d_ws, size_t ws_size,
                              hipStream_t stream) {
    const float* q        = (const float*)d_in[0];
    const float* att1     = (const float*)d_in[1];
    const float* obj_reps = (const float*)d_in[2];
    const int*   tags     = (const int*)d_in[3];
    const float* t_rep    = (const float*)d_in[4];
    const float* W        = (const float*)d_in[5];
    const float* bias_p   = (const float*)d_in[6];
    const int*   t_p      = (const int*)d_in[7];
    float* out = (float*)d_out;

    float* inter = (float*)d_ws;   // 2048*512*4 = 4 MB

    dim3 g1(GN / BN, GM / BM);     // (8, 32) = 256 blocks
    gemm_qw<<<g1, 512, 0, stream>>>(q, W, inter);

    // R8 DIAGNOSTIC: double-launch of K2. Idempotent (writes identical out both
    // times). dur delta vs R1 == T2 (t_rep streams from HBM both passes).
    fused_att<<<2048, 256, 0, stream>>>(att1, obj_reps, tags, t_rep, inter,
                                        bias_p, t_p, out);
    fused_att<<<2048, 256, 0, stream>>>(att1, obj_reps, tags, t_rep, inter,
                                        bias_p, t_p, out);
}

// Round 3
// 238.678 us; speedup vs baseline: 1.0800x; 1.0800x over previous
//
#include <hip/hip_runtime.h>

// Shapes (fixed): B=32, N=64, A=32, O=32, D=512, QD=512
// Inputs: 0:q(B,N,1,QD) f32  1:att1(B,N,A,O) f32  2:obj_reps(B,O,D) f32
//         3:tags(B,N,A) i32  4:t_rep(B,N,A,D) f32 5:W(QD,D) f32
//         6:bias f32 scalar  7:t i32 scalar
// Out: (B,N,O) f32
//
// Restructure: logits[bn,a] = sum_o att1[bn,a,o]*proj[bn,o] + inter[bn,:].t_rep[bn,a,:]
//   proj[bn,o] = inter[bn,:].obj_reps[b,o,:];  inter = q @ W
// Avoids materializing v (134 MB write+read). HBM floor ~= t_rep stream = 134 MB -> ~21 us.
// fp32 everywhere: logits std ~77 with near-one-hot softmax; bf16 noise can flip ties.
//
// Measurement model: same-binary repeatability +/-0.5-1 us. ~2 x 78 us poison fills
// (512 MB each) inside the timed window -> ~156 us fixed floor; plus ~35-40 us of
// harness reset memsets / launch gaps (not addressable from this file).
//
// R7: K1 512-thr NEUTRAL (+0.9) -> K1 throughput-bound, kept.
// R8 DIAGNOSTIC: double-K2 delta = 25.96 us = T2(L2-warm). t_rep stream runs at
//   5.2 TB/s vs 6.9 TB/s the fills prove achievable -> ~4-5 us K2 slack. All other
//   slack is fixed overhead.
// R9 (this): K2 occupancy pin __launch_bounds__(256,8) (cap 64 VGPR -> 32 waves/CU;
//   suspect the 16-deep unrolled tv+ov in-flight set pushed VGPR>64, halving
//   occupancy) + T14 async-split (4 nt prefetch tiles issued BEFORE staging
//   LDS-writes/barrier) + float4 inter staging + bias/t/tags hoisted out of the
//   serial tail. Predict 227-230. Pre-commit: |delta|<=1us -> ROOFLINE next round.

typedef float floatx4 __attribute__((ext_vector_type(4)));

#define GM 2048   // B*N
#define GK 512    // QD
#define GN 512    // D

// ---------------- K1: inter = q @ W  (fp32 tiled GEMM, 64x64 tile, 512 thr, 4x2 utile)
// Per kk-step per thread: ds_read_b128(A, broadcast) + ds_read_b64(B, 2-way alias=free)
// + 8 v_fma_f32. Staging keeps adjacent lanes on adjacent addresses (coalesced) — do
// NOT trade this for wider LDS writes (R4/R5 lesson: -11 us).
#define BM 64
#define BN 64
#define BK 32
#define ASTRIDE (BM + 4)   // 68: rows stay 16B-aligned for ds_read_b128

__global__ __launch_bounds__(512) void gemm_qw(const float* __restrict__ A,
                                               const float* __restrict__ Bm,
                                               float* __restrict__ C) {
    __shared__ float As[BK][ASTRIDE];   // transposed: As[k][m]
    __shared__ float Bs[BK][BN];        // Bs[k][n]

    const int tid = threadIdx.x;
    const int bm0 = blockIdx.y * BM;
    const int bn0 = blockIdx.x * BN;

    // staging: A tile 64x32 = 512 float4 (1/thread), B tile 32x64 = 512 float4 (1/thread)
    const int ar = tid >> 3;            // 0..63 (A row)
    const int ak = (tid & 7) << 2;      // 0..28 (A k, x4) — adjacent lanes 16B apart
    const int br = tid >> 4;            // 0..31 (B k)
    const int bc = (tid & 15) << 2;     // 0..60 (B col, x4) — 16 lanes = 256B contiguous

    const int tx = tid & 31;            // output col pair (cols tx*2, tx*2+1)
    const int ty = tid >> 5;            // output row group (rows ty*4..+3)

    float acc[4][2] = {};

    const float* Ab = A + (long)bm0 * GK;
    const float* Bb = Bm + bn0;

    // prefetch tile 0
    float4 a0 = *(const float4*)(Ab + ar * GK + ak);
    float4 b0 = *(const float4*)(Bb + br * GN + bc);

    for (int k0 = 0; k0 < GK; k0 += BK) {
        __syncthreads();   // previous iteration's LDS reads done
        As[ak + 0][ar] = a0.x; As[ak + 1][ar] = a0.y;
        As[ak + 2][ar] = a0.z; As[ak + 3][ar] = a0.w;
        *(float4*)&Bs[br][bc] = b0;
        __syncthreads();

        if (k0 + BK < GK) {   // register prefetch of next K-tile hides global latency
            a0 = *(const float4*)(Ab + ar * GK + (k0 + BK) + ak);
            b0 = *(const float4*)(Bb + (k0 + BK + br) * GN + bc);
        }

#pragma unroll
        for (int kk = 0; kk < BK; ++kk) {
            float4 av = *(const float4*)&As[kk][ty * 4];   // broadcast across 32 lanes
            float2 bv = *(const float2*)&Bs[kk][tx * 2];   // 2-way bank alias (free)
            acc[0][0] += av.x * bv.x; acc[0][1] += av.x * bv.y;
            acc[1][0] += av.y * bv.x; acc[1][1] += av.y * bv.y;
            acc[2][0] += av.z * bv.x; acc[2][1] += av.z * bv.y;
            acc[3][0] += av.w * bv.x; acc[3][1] += av.w * bv.y;
        }
    }

#pragma unroll
    for (int i = 0; i < 4; ++i) {
        float2 v = make_float2(acc[i][0], acc[i][1]);
        *(float2*)(C + (long)(bm0 + ty * 4 + i) * GN + bn0 + tx * 2) = v;
    }
}

// ---------------- K2: fused proj/tdot/logits/softmax/output (merged + nt + T14) -----
// proj (L2) + tdot (HBM) in ONE loop: 2x memory-level parallelism per wave; inter_s
// read once for both dots. t_rep nontemporal: the 134 MB single-use stream must not
// evict obj_reps/att1 from L2. Measured -4.6 us vs separate loops (prev session).
// R9: occupancy pinned to 8 blocks/CU (32 waves/CU, VGPR<=64) — BW-bound streams
// want max TLP, not max per-thread load depth. 4 t_rep tiles prefetched before the
// staging barrier (their latency hides under the staging round trip + vmcnt drain).
__global__ __launch_bounds__(256, 8) void fused_att(
    const float* __restrict__ att1, const float* __restrict__ obj_reps,
    const int* __restrict__ tags, const float* __restrict__ t_rep,
    const float* __restrict__ inter, const float* __restrict__ bias_p,
    const int* __restrict__ t_p, float* __restrict__ out) {
    const int bn = blockIdx.x;     // 0..2047
    const int b  = bn >> 6;        // N = 64
    const int tid = threadIdx.x;

    __shared__ float inter_s[512];
    __shared__ float att1_s[32 * 33];   // +1 pad: bank-conflict-free rows & cols
    __shared__ float proj_s[32];
    __shared__ float tdot_s[32];
    __shared__ float att2_s[32];

    const int g = tid >> 3;   // 0..31: one row per 8-thread group
    const int j = tid & 7;    // lane within group

    const float* pt = t_rep    + (bn * 32 + g) * 512;   // HBM stream (134 MB total)
    const float* po = obj_reps + (b  * 32 + g) * 512;   // L2-resident (2 MB)

    // ---- head: staging loads to registers ----
    float4 iv;
    if (tid < 128) iv = *(const float4*)(inter + bn * 512 + tid * 4);
    float4 av = *(const float4*)(att1 + bn * 1024 + tid * 4);

    // scalar/tag hoist: these were loaded inside the serial 32-thread tail where
    // their ~200-900 cy latency was fully exposed; here they overlap staging.
    const float bias = *bias_p;
    const float tt   = (float)(*t_p);
    const float mtag = (float)tags[bn * 32 + (tid & 31)];

    // ---- T14: issue first 4 t_rep tiles BEFORE the staging LDS-writes/barrier ----
    floatx4 pf[4];
#pragma unroll
    for (int i = 0; i < 4; ++i)
        pf[i] = __builtin_nontemporal_load((const floatx4*)(pt + i * 32 + j * 4));

    // ---- staging LDS writes + barrier ----
    if (tid < 128) *(float4*)&inter_s[tid * 4] = iv;
    {
        int f = tid * 4;
        int r = f >> 5, c = f & 31;
        att1_s[r * 33 + c + 0] = av.x;
        att1_s[r * 33 + c + 1] = av.y;
        att1_s[r * 33 + c + 2] = av.z;
        att1_s[r * 33 + c + 3] = av.w;
    }
    __syncthreads();

    // ---- main stream: 4 prefetched tiles, then 12 direct ----
    {
        float st = 0.f, sp = 0.f;
#pragma unroll
        for (int i = 0; i < 4; ++i) {
            int d = i * 32 + j * 4;
            float4 ov = *(const float4*)(po + d);
            float i0 = inter_s[d + 0], i1 = inter_s[d + 1];
            float i2 = inter_s[d + 2], i3 = inter_s[d + 3];
            st += pf[i].x * i0 + pf[i].y * i1 + pf[i].z * i2 + pf[i].w * i3;
            sp += ov.x * i0 + ov.y * i1 + ov.z * i2 + ov.w * i3;
        }
#pragma unroll
        for (int i = 4; i < 16; ++i) {
            int d = i * 32 + j * 4;
            floatx4 tv = __builtin_nontemporal_load((const floatx4*)(pt + d));
            float4 ov = *(const float4*)(po + d);
            float i0 = inter_s[d + 0], i1 = inter_s[d + 1];
            float i2 = inter_s[d + 2], i3 = inter_s[d + 3];
            st += tv.x * i0 + tv.y * i1 + tv.z * i2 + tv.w * i3;
            sp += ov.x * i0 + ov.y * i1 + ov.z * i2 + ov.w * i3;
        }
        st += __shfl_xor(st, 1); st += __shfl_xor(st, 2); st += __shfl_xor(st, 4);
        sp += __shfl_xor(sp, 1); sp += __shfl_xor(sp, 2); sp += __shfl_xor(sp, 4);
        if (j == 0) { tdot_s[g] = st; proj_s[g] = sp; }
    }
    __syncthreads();

    // logits + masked softmax + renorm: threads 0..31 (all in wave 0)
    if (tid < 32) {
        const int a = tid;
        float lsum = tdot_s[a] + bias;
#pragma unroll
        for (int o = 0; o < 32; ++o)
            lsum += att1_s[a * 33 + o] * proj_s[o];
        const float m = mtag;
        float x = (lsum / tt) * m;     // masked slots -> logit 0, still in softmax
        float mx = x;
        mx = fmaxf(mx, __shfl_xor(mx, 1));
        mx = fmaxf(mx, __shfl_xor(mx, 2));
        mx = fmaxf(mx, __shfl_xor(mx, 4));
        mx = fmaxf(mx, __shfl_xor(mx, 8));
        mx = fmaxf(mx, __shfl_xor(mx, 16));
        float e = __expf(x - mx);
        float den = e;
        den += __shfl_xor(den, 1);
        den += __shfl_xor(den, 2);
        den += __shfl_xor(den, 4);
        den += __shfl_xor(den, 8);
        den += __shfl_xor(den, 16);
        float s = (e / den) * m;
        float ss = s;
        ss += __shfl_xor(ss, 1);
        ss += __shfl_xor(ss, 2);
        ss += __shfl_xor(ss, 4);
        ss += __shfl_xor(ss, 8);
        ss += __shfl_xor(ss, 16);
        att2_s[a] = s / (ss + 1e-13f);
    }
    __syncthreads();

    // out[bn,o] = sum_a att2[a] * att1[a,o]
    if (tid < 32) {
        const int o = tid;
        float s = 0.f;
#pragma unroll
        for (int a = 0; a < 32; ++a)
            s += att2_s[a] * att1_s[a * 33 + o];
        out[bn * 32 + o] = s;
    }
}

extern "C" void kernel_launch(void* const* d_in, const int* in_sizes, int n_in,
                              void* d_out, int out_size, void* d_ws, size_t ws_size,
                              hipStream_t stream) {
    const float* q        = (const float*)d_in[0];
    const float* att1     = (const float*)d_in[1];
    const float* obj_reps = (const float*)d_in[2];
    const int*   tags     = (const int*)d_in[3];
    const float* t_rep    = (const float*)d_in[4];
    const float* W        = (const float*)d_in[5];
    const float* bias_p   = (const float*)d_in[6];
    const int*   t_p      = (const int*)d_in[7];
    float* out = (float*)d_out;

    float* inter = (float*)d_ws;   // 2048*512*4 = 4 MB

    dim3 g1(GN / BN, GM / BM);     // (8, 32) = 256 blocks
    gemm_qw<<<g1, 512, 0, stream>>>(q, W, inter);

    fused_att<<<2048, 256, 0, stream>>>(att1, obj_reps, tags, t_rep, inter,
                                        bias_p, t_p, out);
}

// Round 4
// 231.387 us; speedup vs baseline: 1.1140x; 1.0315x over previous
//
#include <hip/hip_runtime.h>

// Shapes (fixed): B=32, N=64, A=32, O=32, D=512, QD=512
// Inputs: 0:q(B,N,1,QD) f32  1:att1(B,N,A,O) f32  2:obj_reps(B,O,D) f32
//         3:tags(B,N,A) i32  4:t_rep(B,N,A,D) f32 5:W(QD,D) f32
//         6:bias f32 scalar  7:t i32 scalar
// Out: (B,N,O) f32
//
// Restructure: logits[bn,a] = sum_o att1[bn,a,o]*proj[bn,o] + inter[bn,:].t_rep[bn,a,:]
//   proj[bn,o] = inter[bn,:].obj_reps[b,o,:];  inter = q @ W
// Avoids materializing v (134 MB write+read). HBM floor ~= t_rep stream = 134 MB -> ~21 us.
// fp32 everywhere: logits std ~77 with near-one-hot softmax; bf16 noise can flip ties.
//
// Measurement model: repeatability +/-0.5-1 us. Fixed window overhead ~195 us
// (2 x ~78 us poison fills + ~38 us reset memsets/gaps). Addressable: K1 ~10 us
// (floor ~7), K2 ~26-27 us (floor ~22; R8 double-launch measured T2=25.96 warm).
//
// R7: K1 512-thr NEUTRAL -> K1 throughput-bound.
// R8: DIAGNOSTIC double-K2: T2 = 26 us = 5.2 TB/s vs 6.9 achievable -> ~4-5 us slack.
// R9: REGRESSION +6.9. Bundled {launch_bounds(256,8) pin, 4-tile cross-barrier
//   prefetch, float4 staging, scalar hoist}. Suspect: VGPR cap + cross-barrier
//   live ranges (pf[4]+iv+av) -> scratch spills on a BW-bound kernel.
// R10 (this): unbundle — REVERT pin + cross-barrier prefetch; KEEP float4 inter
//   staging + scalar/tag hoist (1 VGPR, removes exposed tail loads). Predict
//   230-232. Pre-commit: in-band -> ROOFLINE next round; ~238 -> hoist was poison.

typedef float floatx4 __attribute__((ext_vector_type(4)));

#define GM 2048   // B*N
#define GK 512    // QD
#define GN 512    // D

// ---------------- K1: inter = q @ W  (fp32 tiled GEMM, 64x64 tile, 512 thr, 4x2 utile)
// Per kk-step per thread: ds_read_b128(A, broadcast) + ds_read_b64(B, 2-way alias=free)
// + 8 v_fma_f32. Staging keeps adjacent lanes on adjacent addresses (coalesced) — do
// NOT trade this for wider LDS writes (R4/R5 lesson: -11 us).
#define BM 64
#define BN 64
#define BK 32
#define ASTRIDE (BM + 4)   // 68: rows stay 16B-aligned for ds_read_b128

__global__ __launch_bounds__(512) void gemm_qw(const float* __restrict__ A,
                                               const float* __restrict__ Bm,
                                               float* __restrict__ C) {
    __shared__ float As[BK][ASTRIDE];   // transposed: As[k][m]
    __shared__ float Bs[BK][BN];        // Bs[k][n]

    const int tid = threadIdx.x;
    const int bm0 = blockIdx.y * BM;
    const int bn0 = blockIdx.x * BN;

    // staging: A tile 64x32 = 512 float4 (1/thread), B tile 32x64 = 512 float4 (1/thread)
    const int ar = tid >> 3;            // 0..63 (A row)
    const int ak = (tid & 7) << 2;      // 0..28 (A k, x4) — adjacent lanes 16B apart
    const int br = tid >> 4;            // 0..31 (B k)
    const int bc = (tid & 15) << 2;     // 0..60 (B col, x4) — 16 lanes = 256B contiguous

    const int tx = tid & 31;            // output col pair (cols tx*2, tx*2+1)
    const int ty = tid >> 5;            // output row group (rows ty*4..+3)

    float acc[4][2] = {};

    const float* Ab = A + (long)bm0 * GK;
    const float* Bb = Bm + bn0;

    // prefetch tile 0
    float4 a0 = *(const float4*)(Ab + ar * GK + ak);
    float4 b0 = *(const float4*)(Bb + br * GN + bc);

    for (int k0 = 0; k0 < GK; k0 += BK) {
        __syncthreads();   // previous iteration's LDS reads done
        As[ak + 0][ar] = a0.x; As[ak + 1][ar] = a0.y;
        As[ak + 2][ar] = a0.z; As[ak + 3][ar] = a0.w;
        *(float4*)&Bs[br][bc] = b0;
        __syncthreads();

        if (k0 + BK < GK) {   // register prefetch of next K-tile hides global latency
            a0 = *(const float4*)(Ab + ar * GK + (k0 + BK) + ak);
            b0 = *(const float4*)(Bb + (k0 + BK + br) * GN + bc);
        }

#pragma unroll
        for (int kk = 0; kk < BK; ++kk) {
            float4 av = *(const float4*)&As[kk][ty * 4];   // broadcast across 32 lanes
            float2 bv = *(const float2*)&Bs[kk][tx * 2];   // 2-way bank alias (free)
            acc[0][0] += av.x * bv.x; acc[0][1] += av.x * bv.y;
            acc[1][0] += av.y * bv.x; acc[1][1] += av.y * bv.y;
            acc[2][0] += av.z * bv.x; acc[2][1] += av.z * bv.y;
            acc[3][0] += av.w * bv.x; acc[3][1] += av.w * bv.y;
        }
    }

#pragma unroll
    for (int i = 0; i < 4; ++i) {
        float2 v = make_float2(acc[i][0], acc[i][1]);
        *(float2*)(C + (long)(bm0 + ty * 4 + i) * GN + bn0 + tx * 2) = v;
    }
}

// ---------------- K2: fused proj/tdot/logits/softmax/output (merged + nt) ----------
// proj (L2) + tdot (HBM) in ONE loop: 2x memory-level parallelism per wave; inter_s
// read once for both dots. t_rep nontemporal: the 134 MB single-use stream must not
// evict obj_reps/att1 from L2. Measured -4.6 us vs separate loops (prev session).
// R10: NO launch_bounds pin (R9 spill suspect), NO cross-barrier prefetch. Kept:
// float4 inter staging, scalar/tag hoist (loads overlap staging round trip).
__global__ __launch_bounds__(256) void fused_att(
    const float* __restrict__ att1, const float* __restrict__ obj_reps,
    const int* __restrict__ tags, const float* __restrict__ t_rep,
    const float* __restrict__ inter, const float* __restrict__ bias_p,
    const int* __restrict__ t_p, float* __restrict__ out) {
    const int bn = blockIdx.x;     // 0..2047
    const int b  = bn >> 6;        // N = 64
    const int tid = threadIdx.x;

    __shared__ float inter_s[512];
    __shared__ float att1_s[32 * 33];   // +1 pad: bank-conflict-free rows & cols
    __shared__ float proj_s[32];
    __shared__ float tdot_s[32];
    __shared__ float att2_s[32];

    const int g = tid >> 3;   // 0..31: one row per 8-thread group
    const int j = tid & 7;    // lane within group

    // scalar/tag hoist: previously loaded inside the serial 32-thread tail where
    // ~200-900 cy latency was fully exposed; here they overlap the staging loads.
    const float bias = *bias_p;
    const float tt   = (float)(*t_p);
    const float mtag = (float)tags[bn * 32 + (tid & 31)];

    // stage inter row (512 f32, float4) and att1 tile (32x32 f32, padded)
    if (tid < 128) {
        float4 v = *(const float4*)(inter + bn * 512 + tid * 4);
        *(float4*)&inter_s[tid * 4] = v;
    }
    {
        float4 v = *(const float4*)(att1 + bn * 1024 + tid * 4);
        int f = tid * 4;
        int r = f >> 5, c = f & 31;
        att1_s[r * 33 + c + 0] = v.x;
        att1_s[r * 33 + c + 1] = v.y;
        att1_s[r * 33 + c + 2] = v.z;
        att1_s[r * 33 + c + 3] = v.w;
    }
    __syncthreads();

    {
        const float* pt = t_rep    + (bn * 32 + g) * 512;   // HBM stream (134 MB total)
        const float* po = obj_reps + (b  * 32 + g) * 512;   // L2-resident (2 MB)
        float st = 0.f, sp = 0.f;
#pragma unroll
        for (int i = 0; i < 16; ++i) {
            int d = i * 32 + j * 4;
            floatx4 tv = __builtin_nontemporal_load((const floatx4*)(pt + d));
            float4 ov = *(const float4*)(po + d);
            float i0 = inter_s[d + 0], i1 = inter_s[d + 1];
            float i2 = inter_s[d + 2], i3 = inter_s[d + 3];
            st += tv.x * i0 + tv.y * i1 + tv.z * i2 + tv.w * i3;
            sp += ov.x * i0 + ov.y * i1 + ov.z * i2 + ov.w * i3;
        }
        st += __shfl_xor(st, 1); st += __shfl_xor(st, 2); st += __shfl_xor(st, 4);
        sp += __shfl_xor(sp, 1); sp += __shfl_xor(sp, 2); sp += __shfl_xor(sp, 4);
        if (j == 0) { tdot_s[g] = st; proj_s[g] = sp; }
    }
    __syncthreads();

    // logits + masked softmax + renorm: threads 0..31 (all in wave 0)
    if (tid < 32) {
        const int a = tid;
        float lsum = tdot_s[a] + bias;
#pragma unroll
        for (int o = 0; o < 32; ++o)
            lsum += att1_s[a * 33 + o] * proj_s[o];
        const float m = mtag;
        float x = (lsum / tt) * m;     // masked slots -> logit 0, still in softmax
        float mx = x;
        mx = fmaxf(mx, __shfl_xor(mx, 1));
        mx = fmaxf(mx, __shfl_xor(mx, 2));
        mx = fmaxf(mx, __shfl_xor(mx, 4));
        mx = fmaxf(mx, __shfl_xor(mx, 8));
        mx = fmaxf(mx, __shfl_xor(mx, 16));
        float e = __expf(x - mx);
        float den = e;
        den += __shfl_xor(den, 1);
        den += __shfl_xor(den, 2);
        den += __shfl_xor(den, 4);
        den += __shfl_xor(den, 8);
        den += __shfl_xor(den, 16);
        float s = (e / den) * m;
        float ss = s;
        ss += __shfl_xor(ss, 1);
        ss += __shfl_xor(ss, 2);
        ss += __shfl_xor(ss, 4);
        ss += __shfl_xor(ss, 8);
        ss += __shfl_xor(ss, 16);
        att2_s[a] = s / (ss + 1e-13f);
    }
    __syncthreads();

    // out[bn,o] = sum_a att2[a] * att1[a,o]
    if (tid < 32) {
        const int o = tid;
        float s = 0.f;
#pragma unroll
        for (int a = 0; a < 32; ++a)
            s += att2_s[a] * att1_s[a * 33 + o];
        out[bn * 32 + o] = s;
    }
}

extern "C" void kernel_launch(void* const* d_in, const int* in_sizes, int n_in,
                              void* d_out, int out_size, void* d_ws, size_t ws_size,
                              hipStream_t stream) {
    const float* q        = (const float*)d_in[0];
    const float* att1     = (const float*)d_in[1];
    const float* obj_reps = (const float*)d_in[2];
    const int*   tags     = (const int*)d_in[3];
    const float* t_rep    = (const float*)d_in[4];
    const float* W        = (const float*)d_in[5];
    const float* bias_p   = (const float*)d_in[6];
    const int*   t_p      = (const int*)d_in[7];
    float* out = (float*)d_out;

    float* inter = (float*)d_ws;   // 2048*512*4 = 4 MB

    dim3 g1(GN / BN, GM / BM);     // (8, 32) = 256 blocks
    gemm_qw<<<g1, 512, 0, stream>>>(q, W, inter);

    fused_att<<<2048, 256, 0, stream>>>(att1, obj_reps, tags, t_rep, inter,
                                        bias_p, t_p, out);
}